// Round 2
// baseline (479.987 us; speedup 1.0000x reference)
//
#include <hip/hip_runtime.h>
#include <hip/hip_bf16.h>
#include <math.h>

// Problem constants: N=8, L=1024, D=1024, H=16, hd=64, SCALE=0.125
typedef short bf16x8 __attribute__((ext_vector_type(8)));
typedef float f32x4 __attribute__((ext_vector_type(4)));

__device__ __forceinline__ short f2bf(float f) {
  unsigned u = __float_as_uint(f);
  u += 0x7fffu + ((u >> 16) & 1u);          // RNE
  return (short)(u >> 16);
}
__device__ __forceinline__ float bf2f(short h) {
  return __uint_as_float(((unsigned)(unsigned short)h) << 16);
}

typedef __attribute__((address_space(1))) void glob_void;
typedef __attribute__((address_space(3))) void lds_void;
// async global->LDS, 16B per lane; LDS dest = wave-uniform base + lane*16
__device__ __forceinline__ void async16(const void* g, void* l) {
  __builtin_amdgcn_global_load_lds((glob_void*)(uintptr_t)g,
                                   (lds_void*)(unsigned int)(uintptr_t)l,
                                   16, 0, 0);
}

// ---------------- fp32 -> bf16 conversion of x, W_in, W_out ----------------
__global__ void convert3(const float* __restrict__ a, short* __restrict__ ab, int na4,
                         const float* __restrict__ b, short* __restrict__ bb, int nb4,
                         const float* __restrict__ c, short* __restrict__ cb, int nc4) {
  int tid = blockIdx.x * blockDim.x + threadIdx.x;
  int stride = gridDim.x * blockDim.x;
  for (int i = tid; i < na4; i += stride) {
    float4 v = ((const float4*)a)[i];
    ((short4*)ab)[i] = make_short4(f2bf(v.x), f2bf(v.y), f2bf(v.z), f2bf(v.w));
  }
  for (int i = tid; i < nb4; i += stride) {
    float4 v = ((const float4*)b)[i];
    ((short4*)bb)[i] = make_short4(f2bf(v.x), f2bf(v.y), f2bf(v.z), f2bf(v.w));
  }
  for (int i = tid; i < nc4; i += stride) {
    float4 v = ((const float4*)c)[i];
    ((short4*)cb)[i] = make_short4(f2bf(v.x), f2bf(v.y), f2bf(v.z), f2bf(v.w));
  }
}

// ---------------- m97-style B^T GEMM: C[m][n] = sum_k A[m][k]*B[n][k] + bias[n]
// 128x128 tile, BK=64, 256 threads (2x2 waves of 64x64), global_load_lds staging,
// XOR chunk swizzle folded into the staging *global* address (LDS side is fixed).
__global__ __launch_bounds__(256, 2) void gemm_bt(
    const short* __restrict__ A, const short* __restrict__ B,
    const float* __restrict__ bias, float* __restrict__ Cf, short* __restrict__ Cb,
    int M, int N, int K) {
  __shared__ short As[128 * 64];
  __shared__ short Bs[128 * 64];
  const int tid = threadIdx.x;
  const int lane = tid & 63, wave = tid >> 6;
  const int wm = (wave & 1) * 64, wn = (wave >> 1) * 64;
  const int lrow = lane & 15, lgrp = lane >> 4;
  const int m0 = blockIdx.y * 128, n0 = blockIdx.x * 128;
  f32x4 acc[4][4] = {};

  const int srow = tid >> 3;                         // 0..31
  const int schunk = ((tid & 7) ^ (srow & 7)) * 8;   // swizzled source chunk (elems)
  const short* Ag = A + (size_t)(m0 + srow) * K + schunk;
  const short* Bg = B + (size_t)(n0 + srow) * K + schunk;
  short* Al = As + tid * 8;
  short* Bl = Bs + tid * 8;

  for (int k0 = 0; k0 < K; k0 += 64) {
    __syncthreads();  // previous tile's compute done
#pragma unroll
    for (int r = 0; r < 4; ++r) {
      async16(Ag + (size_t)(32 * r) * K + k0, Al + r * 2048);
      async16(Bg + (size_t)(32 * r) * K + k0, Bl + r * 2048);
    }
    __syncthreads();  // vmcnt(0) drained by compiler before barrier
#pragma unroll
    for (int kk = 0; kk < 2; ++kk) {
      bf16x8 af[4], bfr[4];
#pragma unroll
      for (int i = 0; i < 4; ++i) {
        const int ra = wm + i * 16 + lrow;
        af[i] = *(const bf16x8*)&As[ra * 64 + (((kk * 4 + lgrp) ^ (ra & 7)) * 8)];
        const int rb = wn + i * 16 + lrow;
        bfr[i] = *(const bf16x8*)&Bs[rb * 64 + (((kk * 4 + lgrp) ^ (rb & 7)) * 8)];
      }
#pragma unroll
      for (int i = 0; i < 4; ++i)
#pragma unroll
        for (int j = 0; j < 4; ++j)
          acc[i][j] = __builtin_amdgcn_mfma_f32_16x16x32_bf16(af[i], bfr[j], acc[i][j], 0, 0, 0);
    }
  }
  // epilogue: C/D layout col=lane&15, row=(lane>>4)*4+reg
#pragma unroll
  for (int j = 0; j < 4; ++j) {
    const int col = n0 + wn + j * 16 + lrow;
    const float bs = bias[col];
#pragma unroll
    for (int i = 0; i < 4; ++i) {
      const int rb = m0 + wm + i * 16 + lgrp * 4;
#pragma unroll
      for (int r = 0; r < 4; ++r) {
        const float v = acc[i][j][r] + bs;
        if (Cf) Cf[(size_t)(rb + r) * N + col] = v;
        else    Cb[(size_t)(rb + r) * N + col] = f2bf(v);
      }
    }
  }
}

// ---------------- RoPE + head-split + V transpose ----------------
// qkv (8192,3072) bf16 -> qh,kh (n,h,l,d) bf16 (q pre-scaled by 0.125), vt (n,h,d,l) bf16
__global__ __launch_bounds__(256) void rope_kernel(
    const short* __restrict__ qkv, short* __restrict__ qh,
    short* __restrict__ kh, short* __restrict__ vt) {
  __shared__ short vtile[64 * 65];
  const int l0 = blockIdx.x * 64, h = blockIdx.y, n = blockIdx.z;
  const int tid = threadIdx.x;
  const int d = tid & 63, lo = tid >> 6;
  const int j = d & 31;
  const float invf = exp2f(-0.4152410118609203f * (float)j);  // 10000^(-j/32)
  const float sgn = (d < 32) ? -1.0f : 1.0f;
  const int po = ((d + 32) & 63) - d;  // pair offset for rotate_half
  const size_t hb = (size_t)(n * 16 + h) * 1024;
#pragma unroll
  for (int i = 0; i < 16; ++i) {
    const int l = l0 + lo + i * 4;
    const short* row = qkv + (size_t)(n * 1024 + l) * 3072 + h * 64;
    const float qv = bf2f(row[d]),        qp = bf2f(row[d + po]);
    const float kv = bf2f(row[1024 + d]), kp = bf2f(row[1024 + d + po]);
    const float vv = bf2f(row[2048 + d]);
    float s, c;
    sincosf((float)l * invf, &s, &c);
    qh[(hb + l) * 64 + d] = f2bf((qv * c + sgn * qp * s) * 0.125f);
    kh[(hb + l) * 64 + d] = f2bf(kv * c + sgn * kp * s);
    vtile[d * 65 + lo + i * 4] = f2bf(vv);
  }
  __syncthreads();
#pragma unroll
  for (int i = 0; i < 16; ++i) {
    const int dd = lo + i * 4;
    vt[hb * 64 + (size_t)dd * 1024 + l0 + d] = vtile[dd * 65 + d];
  }
}

// ---------------- attention: one block = (n, 16 q-rows), loops all 16 heads ----
// 512 threads / 8 waves; wave owns a 128-col strip of S (16x1024 in registers).
// grid 512 -> 2 blocks/CU -> 16 waves/CU (2x the old TLP).
// P round-trips LDS with pitch 1028 (pitch % 16 == 4 -> conflict-free short writes:
// lgrp groups land on disjoint bank octets). mean-over-heads in registers.
#define PLP 1028
__global__ __launch_bounds__(512, 4) void attn_kernel(
    const short* __restrict__ qh, const short* __restrict__ kh,
    const short* __restrict__ vt, short* __restrict__ attn,
    float* __restrict__ out2) {
  __shared__ __align__(16) short Pl[16 * PLP];
  __shared__ float ssum[8][16];
  __shared__ float Ored[16][64];
  const int bid = blockIdx.x;
  const int n = bid & 7;              // XCD swizzle: same n -> same XCD L2
  const int q0 = (bid >> 3) * 16;
  const int tid = threadIdx.x;
  const int wave = tid >> 6, lane = tid & 63;
  const int lrow = lane & 15, lgrp = lane >> 4;
  const int c0 = wave * 128;          // this wave's S column strip
  const int otile = wave & 3;         // PV: output col tile (16 wide)
  const int khalf = wave >> 2;        // PV: K range half (512 wide)
  f32x4 macc[8] = {};

  for (int h = 0; h < 16; ++h) {
    const size_t hb = (size_t)(n * 16 + h) * 65536;
    const short* qb = qh + hb + (size_t)q0 * 64;
    const short* kb = kh + hb;
    const short* vb = vt + hb;
    // S = (q*SCALE) @ k^T : rows 16, this wave's cols [c0, c0+128)
    f32x4 sacc[8] = {};
#pragma unroll
    for (int kk = 0; kk < 2; ++kk) {
      const bf16x8 af = *(const bf16x8*)(qb + lrow * 64 + kk * 32 + lgrp * 8);
#pragma unroll
      for (int nt = 0; nt < 8; ++nt) {
        const int key = c0 + nt * 16 + lrow;
        const bf16x8 bfr = *(const bf16x8*)(kb + (size_t)key * 64 + kk * 32 + lgrp * 8);
        sacc[nt] = __builtin_amdgcn_mfma_f32_16x16x32_bf16(af, bfr, sacc[nt], 0, 0, 0);
      }
    }
    // exp + row sums (no max subtraction: |S| small, fp32 exp safe)
    float rsum[4] = {0.f, 0.f, 0.f, 0.f};
#pragma unroll
    for (int nt = 0; nt < 8; ++nt)
#pragma unroll
      for (int r = 0; r < 4; ++r) {
        const float e = __expf(sacc[nt][r]);
        sacc[nt][r] = e;
        rsum[r] += e;
      }
#pragma unroll
    for (int off = 1; off < 16; off <<= 1)
#pragma unroll
      for (int r = 0; r < 4; ++r) rsum[r] += __shfl_xor(rsum[r], off, 64);
    __syncthreads();  // guards ssum/Ored/Pl reuse from previous head
    if (lrow == 0) {
#pragma unroll
      for (int r = 0; r < 4; ++r) ssum[wave][lgrp * 4 + r] = rsum[r];
    }
    __syncthreads();
    float inv[4];
#pragma unroll
    for (int r = 0; r < 4; ++r) {
      const int row = lgrp * 4 + r;
      float s = 0.f;
#pragma unroll
      for (int w = 0; w < 8; ++w) s += ssum[w][row];
      inv[r] = 1.0f / s;
    }
    // normalize, accumulate head-mean, write P to LDS (bf16, A-layout source)
#pragma unroll
    for (int nt = 0; nt < 8; ++nt) {
      const int col = c0 + nt * 16 + lrow;
#pragma unroll
      for (int r = 0; r < 4; ++r) {
        const float pv = sacc[nt][r] * inv[r];
        macc[nt][r] += pv;
        Pl[(lgrp * 4 + r) * PLP + col] = f2bf(pv);
      }
    }
    __syncthreads();
    // PV: wave (otile, khalf): out cols [otile*16,+16), K in [khalf*512,+512)
    f32x4 oacc = {};
#pragma unroll
    for (int kt = 0; kt < 16; ++kt) {
      const int kof = khalf * 512 + kt * 32;
      const bf16x8 af = *(const bf16x8*)&Pl[lrow * PLP + kof + lgrp * 8];
      const bf16x8 bfr = *(const bf16x8*)(vb + (size_t)(otile * 16 + lrow) * 1024 + kof + lgrp * 8);
      oacc = __builtin_amdgcn_mfma_f32_16x16x32_bf16(af, bfr, oacc, 0, 0, 0);
    }
    if (khalf == 1) {
#pragma unroll
      for (int r = 0; r < 4; ++r) Ored[lgrp * 4 + r][otile * 16 + lrow] = oacc[r];
    }
    __syncthreads();
    if (khalf == 0) {
#pragma unroll
      for (int r = 0; r < 4; ++r) {
        const int row = lgrp * 4 + r;
        const float v = oacc[r] + Ored[row][otile * 16 + lrow];
        attn[(size_t)(n * 1024 + q0 + row) * 1024 + h * 64 + otile * 16 + lrow] = f2bf(v);
      }
    }
  }
  // write w.mean(axis=1): (N, L, L), value = sum_h(P)/16
#pragma unroll
  for (int nt = 0; nt < 8; ++nt) {
    const int col = c0 + nt * 16 + lrow;
#pragma unroll
    for (int r = 0; r < 4; ++r) {
      const int row = lgrp * 4 + r;
      out2[(size_t)(n * 1024 + q0 + row) * 1024 + col] = macc[nt][r] * 0.0625f;
    }
  }
}

extern "C" void kernel_launch(void* const* d_in, const int* in_sizes, int n_in,
                              void* d_out, int out_size, void* d_ws, size_t ws_size,
                              hipStream_t stream) {
  const float* x  = (const float*)d_in[0];   // (8,1024,1024)
  const float* Wi = (const float*)d_in[1];   // (3072,1024)
  const float* bi = (const float*)d_in[2];   // (3072,)
  const float* Wo = (const float*)d_in[3];   // (1024,1024)
  const float* bo = (const float*)d_in[4];   // (1024,)
  float* out  = (float*)d_out;                       // (8,1024,1024)
  float* out2 = out + (size_t)8 * 1024 * 1024;       // (8,1024,1024) mean attn

  char* p = (char*)d_ws;
  short* xb  = (short*)p; p += (size_t)8388608 * 2;   // x bf16 (reused as attn later)
  short* wb  = (short*)p; p += (size_t)3145728 * 2;   // W_in bf16
  short* wob = (short*)p; p += (size_t)1048576 * 2;   // W_out bf16
  short* qkv = (short*)p; p += (size_t)25165824 * 2;  // (8192,3072) bf16
  short* qh  = (short*)p; p += (size_t)8388608 * 2;   // (n,h,l,d) bf16, pre-scaled
  short* kh  = (short*)p; p += (size_t)8388608 * 2;   // (n,h,l,d) bf16
  short* vt  = (short*)p; p += (size_t)8388608 * 2;   // (n,h,d,l) bf16
  short* attn = xb;  // xb dead after gemm_qkv

  convert3<<<2048, 256, 0, stream>>>(x, xb, 8388608 / 4, Wi, wb, 3145728 / 4,
                                     Wo, wob, 1048576 / 4);
  gemm_bt<<<dim3(24, 64), 256, 0, stream>>>(xb, wb, bi, nullptr, qkv, 8192, 3072, 1024);
  rope_kernel<<<dim3(16, 16, 8), 256, 0, stream>>>(qkv, qh, kh, vt);
  attn_kernel<<<512, 512, 0, stream>>>(qh, kh, vt, attn, out2);
  gemm_bt<<<dim3(8, 64), 256, 0, stream>>>(attn, wob, bo, out, nullptr, 8192, 1024, 1024);
}

// Round 3
// 444.780 us; speedup vs baseline: 1.0792x; 1.0792x over previous
//
#include <hip/hip_runtime.h>
#include <hip/hip_bf16.h>
#include <math.h>

// Problem constants: N=8, L=1024, D=1024, H=16, hd=64, SCALE=0.125
typedef short bf16x8 __attribute__((ext_vector_type(8)));
typedef float f32x4 __attribute__((ext_vector_type(4)));

__device__ __forceinline__ short f2bf(float f) {
  unsigned u = __float_as_uint(f);
  u += 0x7fffu + ((u >> 16) & 1u);          // RNE
  return (short)(u >> 16);
}
__device__ __forceinline__ float bf2f(short h) {
  return __uint_as_float(((unsigned)(unsigned short)h) << 16);
}

typedef __attribute__((address_space(1))) void glob_void;
typedef __attribute__((address_space(3))) void lds_void;
// async global->LDS, 16B per lane; LDS dest = wave-uniform base + lane*16
__device__ __forceinline__ void async16(const void* g, void* l) {
  __builtin_amdgcn_global_load_lds((glob_void*)(uintptr_t)g,
                                   (lds_void*)(unsigned int)(uintptr_t)l,
                                   16, 0, 0);
}

// ---------------- fp32 -> bf16 conversion of x, W_in, W_out ----------------
__global__ void convert3(const float* __restrict__ a, short* __restrict__ ab, int na4,
                         const float* __restrict__ b, short* __restrict__ bb, int nb4,
                         const float* __restrict__ c, short* __restrict__ cb, int nc4) {
  int tid = blockIdx.x * blockDim.x + threadIdx.x;
  int stride = gridDim.x * blockDim.x;
  for (int i = tid; i < na4; i += stride) {
    float4 v = ((const float4*)a)[i];
    ((short4*)ab)[i] = make_short4(f2bf(v.x), f2bf(v.y), f2bf(v.z), f2bf(v.w));
  }
  for (int i = tid; i < nb4; i += stride) {
    float4 v = ((const float4*)b)[i];
    ((short4*)bb)[i] = make_short4(f2bf(v.x), f2bf(v.y), f2bf(v.z), f2bf(v.w));
  }
  for (int i = tid; i < nc4; i += stride) {
    float4 v = ((const float4*)c)[i];
    ((short4*)cb)[i] = make_short4(f2bf(v.x), f2bf(v.y), f2bf(v.z), f2bf(v.w));
  }
}

// ---------------- m97-style B^T GEMM: C[m][n] = sum_k A[m][k]*B[n][k] + bias[n]
__global__ __launch_bounds__(256, 2) void gemm_bt(
    const short* __restrict__ A, const short* __restrict__ B,
    const float* __restrict__ bias, float* __restrict__ Cf, short* __restrict__ Cb,
    int M, int N, int K) {
  __shared__ short As[128 * 64];
  __shared__ short Bs[128 * 64];
  const int tid = threadIdx.x;
  const int lane = tid & 63, wave = tid >> 6;
  const int wm = (wave & 1) * 64, wn = (wave >> 1) * 64;
  const int lrow = lane & 15, lgrp = lane >> 4;
  const int m0 = blockIdx.y * 128, n0 = blockIdx.x * 128;
  f32x4 acc[4][4] = {};

  const int srow = tid >> 3;                         // 0..31
  const int schunk = ((tid & 7) ^ (srow & 7)) * 8;   // swizzled source chunk (elems)
  const short* Ag = A + (size_t)(m0 + srow) * K + schunk;
  const short* Bg = B + (size_t)(n0 + srow) * K + schunk;
  short* Al = As + tid * 8;
  short* Bl = Bs + tid * 8;

  for (int k0 = 0; k0 < K; k0 += 64) {
    __syncthreads();
#pragma unroll
    for (int r = 0; r < 4; ++r) {
      async16(Ag + (size_t)(32 * r) * K + k0, Al + r * 2048);
      async16(Bg + (size_t)(32 * r) * K + k0, Bl + r * 2048);
    }
    __syncthreads();
#pragma unroll
    for (int kk = 0; kk < 2; ++kk) {
      bf16x8 af[4], bfr[4];
#pragma unroll
      for (int i = 0; i < 4; ++i) {
        const int ra = wm + i * 16 + lrow;
        af[i] = *(const bf16x8*)&As[ra * 64 + (((kk * 4 + lgrp) ^ (ra & 7)) * 8)];
        const int rb = wn + i * 16 + lrow;
        bfr[i] = *(const bf16x8*)&Bs[rb * 64 + (((kk * 4 + lgrp) ^ (rb & 7)) * 8)];
      }
#pragma unroll
      for (int i = 0; i < 4; ++i)
#pragma unroll
        for (int j = 0; j < 4; ++j)
          acc[i][j] = __builtin_amdgcn_mfma_f32_16x16x32_bf16(af[i], bfr[j], acc[i][j], 0, 0, 0);
    }
  }
#pragma unroll
  for (int j = 0; j < 4; ++j) {
    const int col = n0 + wn + j * 16 + lrow;
    const float bs = bias[col];
#pragma unroll
    for (int i = 0; i < 4; ++i) {
      const int rb = m0 + wm + i * 16 + lgrp * 4;
#pragma unroll
      for (int r = 0; r < 4; ++r) {
        const float v = acc[i][j][r] + bs;
        if (Cf) Cf[(size_t)(rb + r) * N + col] = v;
        else    Cb[(size_t)(rb + r) * N + col] = f2bf(v);
      }
    }
  }
}

// ---------------- RoPE + head-split + V transpose ----------------
__global__ __launch_bounds__(256) void rope_kernel(
    const short* __restrict__ qkv, short* __restrict__ qh,
    short* __restrict__ kh, short* __restrict__ vt) {
  __shared__ short vtile[64 * 65];
  const int l0 = blockIdx.x * 64, h = blockIdx.y, n = blockIdx.z;
  const int tid = threadIdx.x;
  const int d = tid & 63, lo = tid >> 6;
  const int j = d & 31;
  const float invf = exp2f(-0.4152410118609203f * (float)j);  // 10000^(-j/32)
  const float sgn = (d < 32) ? -1.0f : 1.0f;
  const int po = ((d + 32) & 63) - d;  // pair offset for rotate_half
  const size_t hb = (size_t)(n * 16 + h) * 1024;
#pragma unroll
  for (int i = 0; i < 16; ++i) {
    const int l = l0 + lo + i * 4;
    const short* row = qkv + (size_t)(n * 1024 + l) * 3072 + h * 64;
    const float qv = bf2f(row[d]),        qp = bf2f(row[d + po]);
    const float kv = bf2f(row[1024 + d]), kp = bf2f(row[1024 + d + po]);
    const float vv = bf2f(row[2048 + d]);
    float s, c;
    sincosf((float)l * invf, &s, &c);
    qh[(hb + l) * 64 + d] = f2bf((qv * c + sgn * qp * s) * 0.125f);
    kh[(hb + l) * 64 + d] = f2bf(kv * c + sgn * kp * s);
    vtile[d * 65 + lo + i * 4] = f2bf(vv);
  }
  __syncthreads();
#pragma unroll
  for (int i = 0; i < 16; ++i) {
    const int dd = lo + i * 4;
    vt[hb * 64 + (size_t)dd * 1024 + l0 + d] = vtile[dd * 65 + d];
  }
}

// ---------------- scores: QK^T + softmax for 8 heads; P -> global workspace ----
// block = (n, 16 q-rows), 512 threads / 8 waves, wave owns a 128-col strip of S.
// Only 2 barriers per head (ssum cross-wave reduce); P stores are fire-and-forget.
// macc accumulates normalized P for out2 (mean over heads); `first` selects
// overwrite vs read-modify-write of out2.
__global__ __launch_bounds__(512, 4) void scores_kernel(
    const short* __restrict__ qh, const short* __restrict__ kh,
    short* __restrict__ Pws, float* __restrict__ out2, int h0, int first) {
  __shared__ float ssum[8][16];
  const int bid = blockIdx.x;
  const int n = bid & 7;              // XCD swizzle: same n -> same XCD L2
  const int q0 = (bid >> 3) * 16;
  const int tid = threadIdx.x;
  const int wave = tid >> 6, lane = tid & 63;
  const int lrow = lane & 15, lgrp = lane >> 4;
  const int c0 = wave * 128;          // this wave's S column strip
  f32x4 macc[8] = {};

  for (int hh = 0; hh < 8; ++hh) {
    const int h = h0 + hh;
    const size_t hb = (size_t)(n * 16 + h) * 65536;
    const short* qb = qh + hb + (size_t)q0 * 64;
    const short* kb = kh + hb;
    // S = (q*SCALE) @ k^T : rows 16, this wave's cols [c0, c0+128)
    f32x4 sacc[8] = {};
#pragma unroll
    for (int kk = 0; kk < 2; ++kk) {
      const bf16x8 af = *(const bf16x8*)(qb + lrow * 64 + kk * 32 + lgrp * 8);
#pragma unroll
      for (int nt = 0; nt < 8; ++nt) {
        const int key = c0 + nt * 16 + lrow;
        const bf16x8 bfr = *(const bf16x8*)(kb + (size_t)key * 64 + kk * 32 + lgrp * 8);
        sacc[nt] = __builtin_amdgcn_mfma_f32_16x16x32_bf16(af, bfr, sacc[nt], 0, 0, 0);
      }
    }
    // exp + row sums (no max subtraction: |S| small, fp32 exp safe)
    float rsum[4] = {0.f, 0.f, 0.f, 0.f};
#pragma unroll
    for (int nt = 0; nt < 8; ++nt)
#pragma unroll
      for (int r = 0; r < 4; ++r) {
        const float e = __expf(sacc[nt][r]);
        sacc[nt][r] = e;
        rsum[r] += e;
      }
#pragma unroll
    for (int off = 1; off < 16; off <<= 1)
#pragma unroll
      for (int r = 0; r < 4; ++r) rsum[r] += __shfl_xor(rsum[r], off, 64);
    __syncthreads();  // guards ssum reuse from previous head
    if (lrow == 0) {
#pragma unroll
      for (int r = 0; r < 4; ++r) ssum[wave][lgrp * 4 + r] = rsum[r];
    }
    __syncthreads();
    float inv[4];
#pragma unroll
    for (int r = 0; r < 4; ++r) {
      const int row = lgrp * 4 + r;
      float s = 0.f;
#pragma unroll
      for (int w = 0; w < 8; ++w) s += ssum[w][row];
      inv[r] = 1.0f / s;
    }
    // normalize, accumulate head-mean, store P to workspace (n,hh,q,k)
    short* Pb = Pws + ((size_t)(n * 8 + hh) * 1024 + q0) * 1024;
#pragma unroll
    for (int nt = 0; nt < 8; ++nt) {
      const int col = c0 + nt * 16 + lrow;
#pragma unroll
      for (int r = 0; r < 4; ++r) {
        const float pv = sacc[nt][r] * inv[r];
        macc[nt][r] += pv;
        Pb[(size_t)(lgrp * 4 + r) * 1024 + col] = f2bf(pv);
      }
    }
  }
  // out2 contribution: sum_h(P)/16 (two calls cover 16 heads)
#pragma unroll
  for (int nt = 0; nt < 8; ++nt) {
    const int col = c0 + nt * 16 + lrow;
#pragma unroll
    for (int r = 0; r < 4; ++r) {
      const size_t idx = (size_t)(n * 1024 + q0 + lgrp * 4 + r) * 1024 + col;
      const float prev = first ? 0.0f : out2[idx];
      out2[idx] = prev + macc[nt][r] * 0.0625f;
    }
  }
}

// ---------------- PV GEMM: attn[n,q,h*64+d] = P[n,hh,q,:] @ V^T[n,h,d,:] ------
// 128x64 tile per block for one (n,hh); m97-style LDS pipeline, K=1024, BK=64.
__global__ __launch_bounds__(256, 2) void pv_gemm(
    const short* __restrict__ P, const short* __restrict__ vt,
    short* __restrict__ attn, int h0) {
  __shared__ short Ps[128 * 64];
  __shared__ short Vs[64 * 64];
  const int tid = threadIdx.x;
  const int lane = tid & 63, wave = tid >> 6;
  const int lrow = lane & 15, lgrp = lane >> 4;
  const int q0 = blockIdx.x * 128;
  const int nh = blockIdx.y;          // n*8 + hh
  const int n = nh >> 3, h = h0 + (nh & 7);
  const int wm = wave * 32;           // wave's 32-row strip
  f32x4 acc[2][4] = {};

  const short* Ap = P + (size_t)nh * 1048576 + (size_t)q0 * 1024;
  const short* Bp = vt + (size_t)(n * 16 + h) * 65536;   // 64 rows x 1024 (d,l)

  const int srow = tid >> 3;                        // 0..31
  const int schunk = ((tid & 7) ^ (srow & 7)) * 8;  // XOR-swizzled chunk
  const short* Ag = Ap + (size_t)srow * 1024 + schunk;
  const short* Bg = Bp + (size_t)srow * 1024 + schunk;
  short* Al = Ps + tid * 8;
  short* Vl = Vs + tid * 8;

  for (int k0 = 0; k0 < 1024; k0 += 64) {
    __syncthreads();
#pragma unroll
    for (int r = 0; r < 4; ++r)
      async16(Ag + (size_t)(32 * r) * 1024 + k0, Al + r * 2048);
#pragma unroll
    for (int r = 0; r < 2; ++r)
      async16(Bg + (size_t)(32 * r) * 1024 + k0, Vl + r * 2048);
    __syncthreads();
#pragma unroll
    for (int kk = 0; kk < 2; ++kk) {
      bf16x8 af[2], bfr[4];
#pragma unroll
      for (int i = 0; i < 2; ++i) {
        const int ra = wm + i * 16 + lrow;
        af[i] = *(const bf16x8*)&Ps[ra * 64 + (((kk * 4 + lgrp) ^ (ra & 7)) * 8)];
      }
#pragma unroll
      for (int j = 0; j < 4; ++j) {
        const int rb = j * 16 + lrow;
        bfr[j] = *(const bf16x8*)&Vs[rb * 64 + (((kk * 4 + lgrp) ^ (rb & 7)) * 8)];
      }
#pragma unroll
      for (int i = 0; i < 2; ++i)
#pragma unroll
        for (int j = 0; j < 4; ++j)
          acc[i][j] = __builtin_amdgcn_mfma_f32_16x16x32_bf16(af[i], bfr[j], acc[i][j], 0, 0, 0);
    }
  }
#pragma unroll
  for (int i = 0; i < 2; ++i)
#pragma unroll
    for (int j = 0; j < 4; ++j) {
      const int col = h * 64 + j * 16 + lrow;
#pragma unroll
      for (int r = 0; r < 4; ++r) {
        const int row = q0 + wm + i * 16 + lgrp * 4 + r;
        attn[(size_t)(n * 1024 + row) * 1024 + col] = f2bf(acc[i][j][r]);
      }
    }
}

extern "C" void kernel_launch(void* const* d_in, const int* in_sizes, int n_in,
                              void* d_out, int out_size, void* d_ws, size_t ws_size,
                              hipStream_t stream) {
  const float* x  = (const float*)d_in[0];   // (8,1024,1024)
  const float* Wi = (const float*)d_in[1];   // (3072,1024)
  const float* bi = (const float*)d_in[2];   // (3072,)
  const float* Wo = (const float*)d_in[3];   // (1024,1024)
  const float* bo = (const float*)d_in[4];   // (1024,)
  float* out  = (float*)d_out;                       // (8,1024,1024)
  float* out2 = out + (size_t)8 * 1024 * 1024;       // (8,1024,1024) mean attn

  char* p = (char*)d_ws;
  short* xb  = (short*)p; p += (size_t)8388608 * 2;   // x bf16 (reused as attn later)
  short* wb  = (short*)p; p += (size_t)3145728 * 2;   // W_in bf16
  short* wob = (short*)p; p += (size_t)1048576 * 2;   // W_out bf16
  // union: qkv (50.3 MB, dead after rope) | Pws (134 MB, 8 heads of P)
  short* qkv = (short*)p;
  short* Pws = (short*)p; p += (size_t)8 * 8 * 1024 * 1024 * 2;  // 134 MB
  short* qh  = (short*)p; p += (size_t)8388608 * 2;   // (n,h,l,d) bf16, pre-scaled
  short* kh  = (short*)p; p += (size_t)8388608 * 2;   // (n,h,l,d) bf16
  short* vt  = (short*)p; p += (size_t)8388608 * 2;   // (n,h,d,l) bf16
  short* attn = xb;  // xb dead after gemm_qkv

  convert3<<<2048, 256, 0, stream>>>(x, xb, 8388608 / 4, Wi, wb, 3145728 / 4,
                                     Wo, wob, 1048576 / 4);
  gemm_bt<<<dim3(24, 64), 256, 0, stream>>>(xb, wb, bi, nullptr, qkv, 8192, 3072, 1024);
  rope_kernel<<<dim3(16, 16, 8), 256, 0, stream>>>(qkv, qh, kh, vt);
  scores_kernel<<<512, 512, 0, stream>>>(qh, kh, Pws, out2, 0, 1);
  pv_gemm<<<dim3(8, 64), 256, 0, stream>>>(Pws, vt, attn, 0);
  scores_kernel<<<512, 512, 0, stream>>>(qh, kh, Pws, out2, 8, 0);
  pv_gemm<<<dim3(8, 64), 256, 0, stream>>>(Pws, vt, attn, 8);
  gemm_bt<<<dim3(8, 64), 256, 0, stream>>>(attn, wob, bo, out, nullptr, 8192, 1024, 1024);
}